// Round 2
// baseline (13396.426 us; speedup 1.0000x reference)
//
#include <hip/hip_runtime.h>

// ---------------------------------------------------------------------------
// OGRENet: GraphNet block, fp32 baseline (no fp32 MFMA on CDNA4 -> VALU GEMM).
//   u_r = u @ w_sel^T + b_sel                      [16,256]
//   edge MLP: [E,275] -> 1024 x4 -> 512
//   node MLP1: [E,521] -> 512 -> 512, scatter_mean by row -> agg [N,512]
//   node MLP2: [N,777] -> 512 -> 1
// NOTE: harness passes integer inputs as int32 (edge_index, batch).
// ---------------------------------------------------------------------------

#define NN 20000
#define EE 100000
#define BB 16

__device__ __forceinline__ int clampi(int v, int hi) {
    return v < 0 ? 0 : (v >= hi ? hi - 1 : v);
}

// ------------------------- tiled fp32 GEMM ---------------------------------
// C[M,N] = act(A[M,K] @ Bt[K,N] + bias), Bt row-major (pre-transposed weights)
// 128x128 tile, 256 threads, 8x8 acc per thread in 64+64 split subtiles.
__global__ __launch_bounds__(256) void gemm_bias_act(
    const float* __restrict__ A, int lda,
    const float* __restrict__ Bt, int N,
    const float* __restrict__ bias,
    float* __restrict__ C, int ldc,
    int M, int K, int relu)
{
    __shared__ float As[8][128];
    __shared__ float Bs[8][128];
    const int tid = threadIdx.x;
    const int bm = blockIdx.y * 128;
    const int bn = blockIdx.x * 128;
    const int a_m = tid >> 1;            // 0..127
    const int a_k = (tid & 1) << 2;      // 0 or 4
    const int b_k = tid >> 5;            // 0..7
    const int b_n = (tid & 31) << 2;     // 0..124
    const int tx = tid & 15;
    const int ty = tid >> 4;

    float acc[8][8];
#pragma unroll
    for (int i = 0; i < 8; ++i)
#pragma unroll
        for (int j = 0; j < 8; ++j) acc[i][j] = 0.f;

    const int gm = bm + a_m;
    const float* Aptr = A + (size_t)gm * lda + a_k;
    const float* Bptr = Bt + (size_t)b_k * N + bn + b_n;

    for (int k0 = 0; k0 < K; k0 += 8) {
        float4 av = make_float4(0.f, 0.f, 0.f, 0.f);
        if (gm < M) av = *(const float4*)(Aptr + k0);
        float4 bv = *(const float4*)(Bptr + (size_t)k0 * N);
        __syncthreads();
        As[a_k + 0][a_m] = av.x;
        As[a_k + 1][a_m] = av.y;
        As[a_k + 2][a_m] = av.z;
        As[a_k + 3][a_m] = av.w;
        *(float4*)&Bs[b_k][b_n] = bv;
        __syncthreads();
#pragma unroll
        for (int k = 0; k < 8; ++k) {
            float a0[8], b0[8];
            *(float4*)&a0[0] = *(const float4*)&As[k][ty << 2];
            *(float4*)&a0[4] = *(const float4*)&As[k][64 + (ty << 2)];
            *(float4*)&b0[0] = *(const float4*)&Bs[k][tx << 2];
            *(float4*)&b0[4] = *(const float4*)&Bs[k][64 + (tx << 2)];
#pragma unroll
            for (int i = 0; i < 8; ++i)
#pragma unroll
                for (int j = 0; j < 8; ++j)
                    acc[i][j] = fmaf(a0[i], b0[j], acc[i][j]);
        }
    }

#pragma unroll
    for (int i = 0; i < 8; ++i) {
        int m = bm + ((i < 4) ? ((ty << 2) + i) : (64 + (ty << 2) + (i - 4)));
        if (m >= M) continue;
#pragma unroll
        for (int jh = 0; jh < 2; ++jh) {
            int n = bn + jh * 64 + (tx << 2);
            float4 v;
            v.x = acc[i][jh * 4 + 0] + bias[n + 0];
            v.y = acc[i][jh * 4 + 1] + bias[n + 1];
            v.z = acc[i][jh * 4 + 2] + bias[n + 2];
            v.w = acc[i][jh * 4 + 3] + bias[n + 3];
            if (relu) {
                v.x = fmaxf(v.x, 0.f); v.y = fmaxf(v.y, 0.f);
                v.z = fmaxf(v.z, 0.f); v.w = fmaxf(v.w, 0.f);
            }
            *(float4*)&C[(size_t)m * ldc + n] = v;
        }
    }
}

// ------------------------- helper kernels ----------------------------------

// wt[Kpad,N] = w[N,K]^T, zero-padded rows K..Kpad-1
__global__ void k_transpose_pad(const float* __restrict__ w, float* __restrict__ wt,
                                int N, int K, int Kpad)
{
    int t = blockIdx.x * blockDim.x + threadIdx.x;
    if (t >= Kpad * N) return;
    int k = t / N, n = t - k * N;
    wt[t] = (k < K) ? w[(size_t)n * K + k] : 0.f;
}

// u_r[16,256] = u @ w_sel^T + b_sel. one wave per output element.
__global__ void k_u_r(const float* __restrict__ u, const float* __restrict__ w_sel,
                      const float* __restrict__ b_sel, float* __restrict__ u_r)
{
    int wave = (blockIdx.x * 256 + threadIdx.x) >> 6;
    int lane = threadIdx.x & 63;
    int b = wave >> 8, n = wave & 255;
    const float4* u4 = (const float4*)(u + (size_t)b * 4096);
    const float4* w4 = (const float4*)(w_sel + (size_t)n * 4096);
    float s = 0.f;
    for (int i = lane; i < 1024; i += 64) {
        float4 a = u4[i], c = w4[i];
        s += a.x * c.x + a.y * c.y + a.z * c.z + a.w * c.w;
    }
    for (int off = 32; off; off >>= 1) s += __shfl_down(s, off);
    if (lane == 0) u_r[b * 256 + n] = s + b_sel[n];
}

// e_in[ec,280] = [x[row] | x[col] | edge_attr | u_r[batch[row]] | 0-pad]
__global__ void k_gather_edge_in(const float* __restrict__ x, const float* __restrict__ ea,
                                 const float* __restrict__ u_r,
                                 const int* __restrict__ row,
                                 const int* __restrict__ col,
                                 const int* __restrict__ batch,
                                 float* __restrict__ e_in, int e0, int ec)
{
    int t = blockIdx.x * blockDim.x + threadIdx.x;
    if (t >= ec * 280) return;
    int el = t / 280, c = t - el * 280;
    int e = e0 + el;
    float v = 0.f;
    if (c < 9) {
        int r = clampi(row[e], NN);
        v = x[(size_t)r * 9 + c];
    } else if (c < 18) {
        int cc = clampi(col[e], NN);
        v = x[(size_t)cc * 9 + (c - 9)];
    } else if (c == 18) {
        v = ea[e];
    } else if (c < 275) {
        int r = clampi(row[e], NN);
        int b = clampi(batch[r], BB);
        v = u_r[(size_t)b * 256 + (c - 19)];
    }
    e_in[(size_t)el * 280 + c] = v;
}

// n_in[ec,528] = [x[col] | edge_out | 0-pad]
__global__ void k_gather_node_in(const float* __restrict__ x,
                                 const float* __restrict__ edge_out,
                                 const int* __restrict__ col,
                                 float* __restrict__ n_in, int e0, int ec)
{
    int t = blockIdx.x * blockDim.x + threadIdx.x;
    if (t >= ec * 528) return;
    int el = t / 528, c = t - el * 528;
    float v = 0.f;
    if (c < 9) {
        int cc = clampi(col[e0 + el], NN);
        v = x[(size_t)cc * 9 + c];
    } else if (c < 521) {
        v = edge_out[(size_t)el * 512 + (c - 9)];
    }
    n_in[(size_t)el * 528 + c] = v;
}

// m_in[N,784] = [x | agg/cnt | u_r[batch] | 0-pad]
__global__ void k_gather_m_in(const float* __restrict__ x, const float* __restrict__ agg,
                              const float* __restrict__ cnt, const float* __restrict__ u_r,
                              const int* __restrict__ batch,
                              float* __restrict__ m_in)
{
    int t = blockIdx.x * blockDim.x + threadIdx.x;
    if (t >= NN * 784) return;
    int n = t / 784, c = t - n * 784;
    float v = 0.f;
    if (c < 9) {
        v = x[(size_t)n * 9 + c];
    } else if (c < 521) {
        v = agg[(size_t)n * 512 + (c - 9)] / fmaxf(cnt[n], 1.f);
    } else if (c < 777) {
        int b = clampi(batch[n], BB);
        v = u_r[(size_t)b * 256 + (c - 521)];
    }
    m_in[(size_t)n * 784 + c] = v;
}

__global__ void k_count(const int* __restrict__ row, float* __restrict__ cnt)
{
    int e = blockIdx.x * blockDim.x + threadIdx.x;
    if (e < EE) atomicAdd(&cnt[clampi(row[e], NN)], 1.f);
}

__global__ void k_scatter_add(const float* __restrict__ nh2, const int* __restrict__ row,
                              float* __restrict__ agg, int e0, int ec)
{
    int t = blockIdx.x * blockDim.x + threadIdx.x;
    if (t >= ec * 512) return;
    int el = t >> 9, c = t & 511;
    int r = clampi(row[e0 + el], NN);
    atomicAdd(&agg[(size_t)r * 512 + c], nh2[(size_t)el * 512 + c]);
}

// out[n] = h2[n,:] . mw1 + mb1   (one wave per node)
__global__ void k_final(const float* __restrict__ h2, const float* __restrict__ mw1,
                        const float* __restrict__ mb1, float* __restrict__ out)
{
    int wave = (blockIdx.x * 256 + threadIdx.x) >> 6;
    int lane = threadIdx.x & 63;
    if (wave >= NN) return;
    const float4* h4 = (const float4*)(h2 + (size_t)wave * 512);
    const float4* w4 = (const float4*)mw1;
    float s = 0.f;
#pragma unroll
    for (int i = 0; i < 2; ++i) {
        int f = lane * 2 + i;          // 0..127 -> 512 floats
        float4 a = h4[f], b = w4[f];
        s += a.x * b.x + a.y * b.y + a.z * b.z + a.w * b.w;
    }
    for (int off = 32; off; off >>= 1) s += __shfl_down(s, off);
    if (lane == 0) out[wave] = s + mb1[0];
}

// ------------------------------- host --------------------------------------

static inline void gemm(hipStream_t s, const float* A, int lda, const float* Bt, int N,
                        const float* bias, float* C, int ldc, int M, int K, int relu)
{
    dim3 g(N / 128, (M + 127) / 128);
    hipLaunchKernelGGL(gemm_bias_act, g, dim3(256), 0, s, A, lda, Bt, N, bias, C, ldc, M, K, relu);
}

extern "C" void kernel_launch(void* const* d_in, const int* in_sizes, int n_in,
                              void* d_out, int out_size, void* d_ws, size_t ws_size,
                              hipStream_t stream)
{
    const float* x     = (const float*)d_in[0];
    const int*   ei    = (const int*)d_in[1];     // int32 per harness contract
    const float* ea    = (const float*)d_in[2];
    const float* u     = (const float*)d_in[3];
    const int*   batch = (const int*)d_in[4];     // int32 per harness contract
    const float* w_sel = (const float*)d_in[5];
    const float* b_sel = (const float*)d_in[6];
    const float* ew0 = (const float*)d_in[7];   const float* eb0 = (const float*)d_in[8];
    const float* ew1 = (const float*)d_in[9];   const float* eb1 = (const float*)d_in[10];
    const float* ew2 = (const float*)d_in[11];  const float* eb2 = (const float*)d_in[12];
    const float* ew3 = (const float*)d_in[13];  const float* eb3 = (const float*)d_in[14];
    const float* ew4 = (const float*)d_in[15];  const float* eb4 = (const float*)d_in[16];
    const float* nw0 = (const float*)d_in[17];  const float* nb0 = (const float*)d_in[18];
    const float* nw1 = (const float*)d_in[19];  const float* nb1 = (const float*)d_in[20];
    const float* mw0 = (const float*)d_in[21];  const float* mb0 = (const float*)d_in[22];
    const float* mw1 = (const float*)d_in[23];  const float* mb1 = (const float*)d_in[24];

    const int* row = ei;
    const int* col = ei + EE;

    // ---- workspace layout (floats), adaptive edge-chunking by ws_size ----
    const size_t fixedF =
        20000                      // cnt
        + (size_t)NN * 512         // agg
        + 16 * 256                 // u_r
        + 280 * 1024 + 3 * 1024 * 1024 + 1024 * 512   // edge weights (padded)
        + 528 * 512 + 512 * 512 + 784 * 512;          // node weights (padded)

    static const int chunkOpts[] = {4, 8, 10, 20, 25, 50};
    int EC = EE / 50;
    size_t szA = 0, szB = 0, szC = 0;
    for (int ci = 0; ci < 6; ++ci) {
        int ec = EE / chunkOpts[ci];
        size_t a = (size_t)ec * 1024; if (a < (size_t)NN * 784) a = (size_t)NN * 784;
        size_t b = (size_t)ec * 1024; if (b < (size_t)NN * 512) b = (size_t)NN * 512;
        size_t c = (size_t)ec * 1024;
        if ((fixedF + a + b + c) * sizeof(float) <= ws_size) { EC = ec; szA = a; szB = b; szC = c; break; }
    }
    if (szA == 0) {  // smallest option anyway; harness ws should cover it
        szA = (size_t)NN * 784; szB = (size_t)NN * 512; szC = (size_t)EC * 1024;
        if ((size_t)EC * 1024 > szA) szA = (size_t)EC * 1024;
        if ((size_t)EC * 1024 > szB) szB = (size_t)EC * 1024;
    }
    const int NCH = EE / EC;

    float* W = (float*)d_ws;
    float* cnt  = W;                    size_t o = 20000;
    float* agg  = W + o;                o += (size_t)NN * 512;
    float* u_r  = W + o;                o += 16 * 256;
    float* wt0  = W + o;                o += 280 * 1024;
    float* wt1  = W + o;                o += 1024 * 1024;
    float* wt2  = W + o;                o += 1024 * 1024;
    float* wt3  = W + o;                o += 1024 * 1024;
    float* wt4  = W + o;                o += 1024 * 512;
    float* wtn0 = W + o;                o += 528 * 512;
    float* wtn1 = W + o;                o += 512 * 512;
    float* wtm0 = W + o;                o += 784 * 512;
    float* bufA = W + o;                o += szA;
    float* bufB = W + o;                o += szB;
    float* bufC = W + o;

    // zero cnt + agg (contiguous at workspace start)
    hipMemsetAsync(cnt, 0, (20000 + (size_t)NN * 512) * sizeof(float), stream);

    // u_r
    hipLaunchKernelGGL(k_u_r, dim3(1024), dim3(256), 0, stream, u, w_sel, b_sel, u_r);

    // weight transposes (zero-padded K)
    auto tr = [&](const float* w, float* wt, int N, int K, int Kpad) {
        int tot = Kpad * N;
        hipLaunchKernelGGL(k_transpose_pad, dim3((tot + 255) / 256), dim3(256), 0, stream,
                           w, wt, N, K, Kpad);
    };
    tr(ew0, wt0, 1024, 275, 280);
    tr(ew1, wt1, 1024, 1024, 1024);
    tr(ew2, wt2, 1024, 1024, 1024);
    tr(ew3, wt3, 512, 1024, 1024);
    tr(ew4, wt4, 512, 1024, 1024);
    // NOTE: ew3 is 1024x1024 -> N=1024; fix the call above properly:
    // (kept explicit below to avoid confusion)

    // redo correct transposes for wt3 (1024 out) — overwrite
    hipLaunchKernelGGL(k_transpose_pad, dim3((1024 * 1024 + 255) / 256), dim3(256), 0, stream,
                       ew3, wt3, 1024, 1024, 1024);
    tr(nw0, wtn0, 512, 521, 528);
    tr(nw1, wtn1, 512, 512, 512);
    tr(mw0, wtm0, 512, 777, 784);

    // edge counts per destination node (row)
    hipLaunchKernelGGL(k_count, dim3((EE + 255) / 256), dim3(256), 0, stream, row, cnt);

    // edge + node-MLP1 pipeline, chunked over edges
    for (int ch = 0; ch < NCH; ++ch) {
        int e0 = ch * EC;
        // e_in -> bufC [EC,280]
        hipLaunchKernelGGL(k_gather_edge_in, dim3((EC * 280 + 255) / 256), dim3(256), 0, stream,
                           x, ea, u_r, row, col, batch, bufC, e0, EC);
        gemm(stream, bufC, 280, wt0, 1024, eb0, bufA, 1024, EC, 280, 1);
        gemm(stream, bufA, 1024, wt1, 1024, eb1, bufB, 1024, EC, 1024, 1);
        gemm(stream, bufB, 1024, wt2, 1024, eb2, bufA, 1024, EC, 1024, 1);
        gemm(stream, bufA, 1024, wt3, 1024, eb3, bufB, 1024, EC, 1024, 1);
        gemm(stream, bufB, 1024, wt4, 512, eb4, bufC, 512, EC, 1024, 0);  // edge_out -> bufC
        // n_in -> bufA [EC,528]
        hipLaunchKernelGGL(k_gather_node_in, dim3((EC * 528 + 255) / 256), dim3(256), 0, stream,
                           x, bufC, col, bufA, e0, EC);
        gemm(stream, bufA, 528, wtn0, 512, nb0, bufB, 512, EC, 528, 1);
        gemm(stream, bufB, 512, wtn1, 512, nb1, bufC, 512, EC, 512, 1);   // nh2 -> bufC
        hipLaunchKernelGGL(k_scatter_add, dim3((EC * 512 + 255) / 256), dim3(256), 0, stream,
                           bufC, row, agg, e0, EC);
    }

    // node MLP2
    hipLaunchKernelGGL(k_gather_m_in, dim3((NN * 784 + 255) / 256), dim3(256), 0, stream,
                       x, agg, cnt, u_r, batch, bufA);
    gemm(stream, bufA, 784, wtm0, 512, mb0, bufB, 512, NN, 784, 1);
    hipLaunchKernelGGL(k_final, dim3((NN + 3) / 4), dim3(256), 0, stream,
                       bufB, mw1, mb1, (float*)d_out);
}

// Round 3
// 3744.760 us; speedup vs baseline: 3.5774x; 3.5774x over previous
//
#include <hip/hip_runtime.h>

// ---------------------------------------------------------------------------
// OGRENet GraphNet block — f16 MFMA GEMM (fp32 accumulate) version.
//   u_r = u @ w_sel^T + b_sel (fp32)               [16,256]
//   edge MLP: [E,275->288p] -> 1024 x4 -> 512      (f16 mfma)
//   node MLP1: [E,521->544p] -> 512 -> 512 (f32 out), scatter_mean -> agg
//   node MLP2: [N,777->800p] -> 512 (f32 out) -> 1 (fp32 wave-dot)
// Weights stay [N][K] row-major (B^T GEMM: both operands K-contiguous).
// ---------------------------------------------------------------------------

#define NN 20000
#define EE 100000
#define BB 16

typedef _Float16 f16x8 __attribute__((ext_vector_type(8)));
typedef float f32x4 __attribute__((ext_vector_type(4)));

__device__ __forceinline__ int clampi(int v, int hi) {
    return v < 0 ? 0 : (v >= hi ? hi - 1 : v);
}

// async global->LDS, 16B per lane. LDS dest = wave-uniform base + lane*16.
__device__ __forceinline__ void gld_lds16(const void* g, void* l) {
    __builtin_amdgcn_global_load_lds(
        (const __attribute__((address_space(1))) unsigned int*)g,
        (__attribute__((address_space(3))) unsigned int*)l, 16, 0, 0);
}

// ------------------------- f16 MFMA GEMM -----------------------------------
// C[M,N] = act(A[M,K] @ W^T + bias); A [M][lda] f16, W [N][ldb] f16 (K-contig).
// 128x128 tile, 256 thr = 4 waves, each wave 64x64 = 4x4 mfma_16x16x32 tiles.
// LDS chunk layout: tile = 512 chunks of 16B at [kgroup(0..3)][row(0..127)];
// frag read for lane l: chunk (l>>4)*128 + tilerow + (l&15)  -> conflict-free.
__global__ __launch_bounds__(256) void gemm_f16(
    const _Float16* __restrict__ A, int lda,
    const _Float16* __restrict__ Wt, int ldb,
    const float* __restrict__ bias,
    void* __restrict__ C, int ldc,
    int M, int Kpad, int relu, int f32out)
{
    __shared__ _Float16 As[4096];   // 512 chunks * 8 f16 = 8 KB
    __shared__ _Float16 Bs[4096];
    const int tid  = threadIdx.x;
    const int lane = tid & 63;
    const int wid  = tid >> 6;
    const int bm = blockIdx.y << 7;
    const int bn = blockIdx.x << 7;
    const int wm = (wid & 1) << 6;       // wave row offset in tile
    const int wn = (wid >> 1) << 6;      // wave col offset in tile

    f32x4 acc[4][4];
#pragma unroll
    for (int i = 0; i < 4; ++i)
#pragma unroll
        for (int j = 0; j < 4; ++j) acc[i][j] = (f32x4){0.f, 0.f, 0.f, 0.f};

    // staging: chunk q = inst*256 + tid; kg = q>>7; r = q&127
    const int q0 = tid, q1 = 256 + tid;
    const int r0 = q0 & 127, kg0 = q0 >> 7;
    const int r1 = q1 & 127, kg1 = q1 >> 7;
    int am0 = bm + r0; if (am0 >= M) am0 = M - 1;   // clamp (stores masked)
    int am1 = bm + r1; if (am1 >= M) am1 = M - 1;
    const _Float16* ga0 = A + (size_t)am0 * lda + (kg0 << 3);
    const _Float16* ga1 = A + (size_t)am1 * lda + (kg1 << 3);
    const _Float16* gb0 = Wt + (size_t)(bn + r0) * ldb + (kg0 << 3);
    const _Float16* gb1 = Wt + (size_t)(bn + r1) * ldb + (kg1 << 3);
    // wave-uniform LDS bases (chunk index = inst*256 + wid*64 + lane)
    _Float16* la0 = As + ((wid * 64) << 3);
    _Float16* la1 = As + ((256 + wid * 64) << 3);
    _Float16* lb0 = Bs + ((wid * 64) << 3);
    _Float16* lb1 = Bs + ((256 + wid * 64) << 3);

    const int kq  = (lane >> 4) * 128;   // chunk row of my k-group
    const int l15 = lane & 15;

    for (int k0 = 0; k0 < Kpad; k0 += 32) {
        __syncthreads();                  // prev iter frag reads done
        gld_lds16(ga0, la0);
        gld_lds16(ga1, la1);
        gld_lds16(gb0, lb0);
        gld_lds16(gb1, lb1);
        ga0 += 32; ga1 += 32; gb0 += 32; gb1 += 32;
        __syncthreads();                  // staging visible

        f16x8 af[4], bf[4];
#pragma unroll
        for (int i = 0; i < 4; ++i)
            af[i] = *(const f16x8*)(As + (size_t)((kq + wm + i * 16 + l15) << 3));
#pragma unroll
        for (int j = 0; j < 4; ++j)
            bf[j] = *(const f16x8*)(Bs + (size_t)((kq + wn + j * 16 + l15) << 3));
#pragma unroll
        for (int i = 0; i < 4; ++i)
#pragma unroll
            for (int j = 0; j < 4; ++j)
                acc[i][j] = __builtin_amdgcn_mfma_f32_16x16x32_f16(af[i], bf[j], acc[i][j], 0, 0, 0);
    }

    // epilogue: C/D layout col = lane&15, row = (lane>>4)*4 + reg
    const int l4 = (lane >> 4) << 2;
#pragma unroll
    for (int j = 0; j < 4; ++j) {
        const int col = bn + wn + j * 16 + l15;
        const float bv = bias[col];
#pragma unroll
        for (int i = 0; i < 4; ++i) {
            const int mbase = bm + wm + i * 16 + l4;
#pragma unroll
            for (int v = 0; v < 4; ++v) {
                const int m = mbase + v;
                if (m >= M) continue;
                float val = acc[i][j][v] + bv;
                if (relu) val = fmaxf(val, 0.f);
                if (f32out) ((float*)C)[(size_t)m * ldc + col] = val;
                else        ((_Float16*)C)[(size_t)m * ldc + col] = (_Float16)val;
            }
        }
    }
}

// ------------------------- helper kernels ----------------------------------

// wh[N,Kpad] f16 = w[N,K] fp32, zero-padded K..Kpad-1
__global__ void k_w2h(const float* __restrict__ w, _Float16* __restrict__ wh,
                      int N, int K, int Kpad)
{
    int t = blockIdx.x * blockDim.x + threadIdx.x;
    if (t >= N * Kpad) return;
    int n = t / Kpad, k = t - n * Kpad;
    wh[t] = (k < K) ? (_Float16)w[(size_t)n * K + k] : (_Float16)0.f;
}

// u_r[16,256] fp32 = u @ w_sel^T + b_sel. one wave per output element.
__global__ void k_u_r(const float* __restrict__ u, const float* __restrict__ w_sel,
                      const float* __restrict__ b_sel, float* __restrict__ u_r)
{
    int wave = (blockIdx.x * 256 + threadIdx.x) >> 6;
    int lane = threadIdx.x & 63;
    int b = wave >> 8, n = wave & 255;
    const float4* u4 = (const float4*)(u + (size_t)b * 4096);
    const float4* w4 = (const float4*)(w_sel + (size_t)n * 4096);
    float s = 0.f;
    for (int i = lane; i < 1024; i += 64) {
        float4 a = u4[i], c = w4[i];
        s += a.x * c.x + a.y * c.y + a.z * c.z + a.w * c.w;
    }
    for (int off = 32; off; off >>= 1) s += __shfl_down(s, off);
    if (lane == 0) u_r[b * 256 + n] = s + b_sel[n];
}

// e_in[ec,288] f16 = [x[row] | x[col] | edge_attr | u_r[batch[row]] | 0-pad]
__global__ void k_gather_edge_in(const float* __restrict__ x, const float* __restrict__ ea,
                                 const float* __restrict__ u_r,
                                 const int* __restrict__ row, const int* __restrict__ col,
                                 const int* __restrict__ batch,
                                 _Float16* __restrict__ e_in, int e0, int ec)
{
    int t = blockIdx.x * blockDim.x + threadIdx.x;
    if (t >= ec * 288) return;
    int el = t / 288, c = t - el * 288;
    int e = e0 + el;
    float v = 0.f;
    if (c < 9) {
        v = x[(size_t)clampi(row[e], NN) * 9 + c];
    } else if (c < 18) {
        v = x[(size_t)clampi(col[e], NN) * 9 + (c - 9)];
    } else if (c == 18) {
        v = ea[e];
    } else if (c < 275) {
        int b = clampi(batch[clampi(row[e], NN)], BB);
        v = u_r[(size_t)b * 256 + (c - 19)];
    }
    e_in[(size_t)el * 288 + c] = (_Float16)v;
}

// n_in[ec,544] f16 = [x[col] | edge_out(f16) | 0-pad]
__global__ void k_gather_node_in(const float* __restrict__ x,
                                 const _Float16* __restrict__ edge_out,
                                 const int* __restrict__ col,
                                 _Float16* __restrict__ n_in, int e0, int ec)
{
    int t = blockIdx.x * blockDim.x + threadIdx.x;
    if (t >= ec * 544) return;
    int el = t / 544, c = t - el * 544;
    _Float16 v = (_Float16)0.f;
    if (c < 9)        v = (_Float16)x[(size_t)clampi(col[e0 + el], NN) * 9 + c];
    else if (c < 521) v = edge_out[(size_t)el * 512 + (c - 9)];
    n_in[(size_t)el * 544 + c] = v;
}

// m_in[N,800] f16 = [x | agg/cnt | u_r[batch] | 0-pad]
__global__ void k_gather_m_in(const float* __restrict__ x, const float* __restrict__ agg,
                              const float* __restrict__ cnt, const float* __restrict__ u_r,
                              const int* __restrict__ batch, _Float16* __restrict__ m_in)
{
    int t = blockIdx.x * blockDim.x + threadIdx.x;
    if (t >= NN * 800) return;
    int n = t / 800, c = t - n * 800;
    float v = 0.f;
    if (c < 9)        v = x[(size_t)n * 9 + c];
    else if (c < 521) v = agg[(size_t)n * 512 + (c - 9)] / fmaxf(cnt[n], 1.f);
    else if (c < 777) v = u_r[(size_t)clampi(batch[n], BB) * 256 + (c - 521)];
    m_in[(size_t)n * 800 + c] = (_Float16)v;
}

__global__ void k_count(const int* __restrict__ row, float* __restrict__ cnt)
{
    int e = blockIdx.x * blockDim.x + threadIdx.x;
    if (e < EE) atomicAdd(&cnt[clampi(row[e], NN)], 1.f);
}

__global__ void k_scatter_add(const float* __restrict__ nh2, const int* __restrict__ row,
                              float* __restrict__ agg, int e0, int ec)
{
    int t = blockIdx.x * blockDim.x + threadIdx.x;
    if (t >= ec * 512) return;
    int el = t >> 9, c = t & 511;
    int r = clampi(row[e0 + el], NN);
    atomicAdd(&agg[(size_t)r * 512 + c], nh2[(size_t)el * 512 + c]);
}

// out[n] = h2[n,:] . mw1 + mb1 (fp32, one wave per node)
__global__ void k_final(const float* __restrict__ h2, const float* __restrict__ mw1,
                        const float* __restrict__ mb1, float* __restrict__ out)
{
    int wave = (blockIdx.x * 256 + threadIdx.x) >> 6;
    int lane = threadIdx.x & 63;
    if (wave >= NN) return;
    const float4* h4 = (const float4*)(h2 + (size_t)wave * 512);
    const float4* w4 = (const float4*)mw1;
    float s = 0.f;
#pragma unroll
    for (int i = 0; i < 2; ++i) {
        int f = lane * 2 + i;
        float4 a = h4[f], b = w4[f];
        s += a.x * b.x + a.y * b.y + a.z * b.z + a.w * b.w;
    }
    for (int off = 32; off; off >>= 1) s += __shfl_down(s, off);
    if (lane == 0) out[wave] = s + mb1[0];
}

// ------------------------------- host --------------------------------------

static inline void gemmF(hipStream_t s, const _Float16* A, int lda, const _Float16* Wt, int ldb,
                         const float* bias, void* C, int ldc, int M, int N, int K,
                         int relu, int f32out)
{
    dim3 g(N / 128, (M + 127) / 128);
    hipLaunchKernelGGL(gemm_f16, g, dim3(256), 0, s, A, lda, Wt, ldb, bias, C, ldc, M, K, relu, f32out);
}

#define GRID1(n) dim3(((n) + 255) / 256)

extern "C" void kernel_launch(void* const* d_in, const int* in_sizes, int n_in,
                              void* d_out, int out_size, void* d_ws, size_t ws_size,
                              hipStream_t stream)
{
    const float* x     = (const float*)d_in[0];
    const int*   ei    = (const int*)d_in[1];
    const float* ea    = (const float*)d_in[2];
    const float* u     = (const float*)d_in[3];
    const int*   batch = (const int*)d_in[4];
    const float* w_sel = (const float*)d_in[5];
    const float* b_sel = (const float*)d_in[6];
    const float* ew0 = (const float*)d_in[7];   const float* eb0 = (const float*)d_in[8];
    const float* ew1 = (const float*)d_in[9];   const float* eb1 = (const float*)d_in[10];
    const float* ew2 = (const float*)d_in[11];  const float* eb2 = (const float*)d_in[12];
    const float* ew3 = (const float*)d_in[13];  const float* eb3 = (const float*)d_in[14];
    const float* ew4 = (const float*)d_in[15];  const float* eb4 = (const float*)d_in[16];
    const float* nw0 = (const float*)d_in[17];  const float* nb0 = (const float*)d_in[18];
    const float* nw1 = (const float*)d_in[19];  const float* nb1 = (const float*)d_in[20];
    const float* mw0 = (const float*)d_in[21];  const float* mb0 = (const float*)d_in[22];
    const float* mw1 = (const float*)d_in[23];  const float* mb1 = (const float*)d_in[24];

    const int* row = ei;
    const int* col = ei + EE;

    // ---- workspace (bytes, 256B-aligned regions) ----
    char* W = (char*)d_ws;
    size_t off = 0;
    auto alloc = [&](size_t bytes) -> char* {
        char* p = W + off;
        off = (off + bytes + 255) & ~(size_t)255;
        return p;
    };
    float*     cnt  = (float*)alloc(20000 * 4);
    float*     agg  = (float*)alloc((size_t)NN * 512 * 4);
    const size_t zeroBytes = off;                 // cnt+agg contiguous from W
    float*     u_r  = (float*)alloc(16 * 256 * 4);
    _Float16*  wh0  = (_Float16*)alloc((size_t)1024 * 288 * 2);
    _Float16*  wh1  = (_Float16*)alloc((size_t)1024 * 1024 * 2);
    _Float16*  wh2  = (_Float16*)alloc((size_t)1024 * 1024 * 2);
    _Float16*  wh3  = (_Float16*)alloc((size_t)1024 * 1024 * 2);
    _Float16*  wh4  = (_Float16*)alloc((size_t)512 * 1024 * 2);
    _Float16*  whn0 = (_Float16*)alloc((size_t)512 * 544 * 2);
    _Float16*  whn1 = (_Float16*)alloc((size_t)512 * 512 * 2);
    _Float16*  whm0 = (_Float16*)alloc((size_t)512 * 800 * 2);
    const size_t fixedBytes = off;

    // pick largest edge chunk that fits (depends only on ws_size -> capture-safe)
    static const int ecOpts[] = {100000, 50000, 25000, 12500, 10000, 4000};
    int EC = 4000;
    for (int i = 0; i < 6; ++i) {
        int ec = ecOpts[i];
        size_t a = (size_t)ec * 1024 * 2; if (a < (size_t)NN * 800 * 2) a = (size_t)NN * 800 * 2;
        size_t b = (size_t)ec * 1024 * 2; if (b < (size_t)NN * 512 * 4) b = (size_t)NN * 512 * 4;
        size_t c = (size_t)ec * 512 * 4;
        if (fixedBytes + a + b + c + 1024 <= ws_size) { EC = ec; break; }
    }
    size_t szA = (size_t)EC * 1024 * 2; if (szA < (size_t)NN * 800 * 2) szA = (size_t)NN * 800 * 2;
    size_t szB = (size_t)EC * 1024 * 2; if (szB < (size_t)NN * 512 * 4) szB = (size_t)NN * 512 * 4;
    size_t szC = (size_t)EC * 512 * 4;
    char* bufA = alloc(szA);
    char* bufB = alloc(szB);
    char* bufC = alloc(szC);
    const int NCH = EE / EC;

    // zero cnt+agg
    hipMemsetAsync(W, 0, zeroBytes, stream);

    // u_r (fp32)
    hipLaunchKernelGGL(k_u_r, dim3(1024), dim3(256), 0, stream, u, w_sel, b_sel, u_r);

    // weight fp32 -> f16 (K padded to x32)
    auto cvt = [&](const float* w, _Float16* wh, int N, int K, int Kpad) {
        hipLaunchKernelGGL(k_w2h, GRID1(N * Kpad), dim3(256), 0, stream, w, wh, N, K, Kpad);
    };
    cvt(ew0, wh0, 1024, 275, 288);
    cvt(ew1, wh1, 1024, 1024, 1024);
    cvt(ew2, wh2, 1024, 1024, 1024);
    cvt(ew3, wh3, 1024, 1024, 1024);
    cvt(ew4, wh4, 512, 1024, 1024);
    cvt(nw0, whn0, 512, 521, 544);
    cvt(nw1, whn1, 512, 512, 512);
    cvt(mw0, whm0, 512, 777, 800);

    hipLaunchKernelGGL(k_count, GRID1(EE), dim3(256), 0, stream, row, cnt);

    for (int ch = 0; ch < NCH; ++ch) {
        int e0 = ch * EC;
        hipLaunchKernelGGL(k_gather_edge_in, GRID1(EC * 288), dim3(256), 0, stream,
                           x, ea, u_r, row, col, batch, (_Float16*)bufC, e0, EC);
        gemmF(stream, (_Float16*)bufC, 288,  wh0, 288,  eb0, bufA, 1024, EC, 1024, 288, 1, 0);
        gemmF(stream, (_Float16*)bufA, 1024, wh1, 1024, eb1, bufB, 1024, EC, 1024, 1024, 1, 0);
        gemmF(stream, (_Float16*)bufB, 1024, wh2, 1024, eb2, bufA, 1024, EC, 1024, 1024, 1, 0);
        gemmF(stream, (_Float16*)bufA, 1024, wh3, 1024, eb3, bufB, 1024, EC, 1024, 1024, 1, 0);
        gemmF(stream, (_Float16*)bufB, 1024, wh4, 1024, eb4, bufC, 512, EC, 512, 1024, 0, 0);
        hipLaunchKernelGGL(k_gather_node_in, GRID1(EC * 544), dim3(256), 0, stream,
                           x, (const _Float16*)bufC, col, (_Float16*)bufA, e0, EC);
        gemmF(stream, (_Float16*)bufA, 544, whn0, 544, nb0, bufB, 512, EC, 512, 544, 1, 0);
        gemmF(stream, (_Float16*)bufB, 512, whn1, 512, nb1, bufC, 512, EC, 512, 512, 1, 1); // f32 out
        hipLaunchKernelGGL(k_scatter_add, GRID1(EC * 512), dim3(256), 0, stream,
                           (const float*)bufC, row, agg, e0, EC);
    }

    hipLaunchKernelGGL(k_gather_m_in, GRID1(NN * 800), dim3(256), 0, stream,
                       x, agg, cnt, u_r, batch, (_Float16*)bufA);
    gemmF(stream, (_Float16*)bufA, 800, whm0, 800, mb0, bufB, 512, NN, 512, 800, 1, 1); // f32 out
    hipLaunchKernelGGL(k_final, dim3((NN + 3) / 4), dim3(256), 0, stream,
                       (const float*)bufB, mw1, mb1, (float*)d_out);
}

// Round 4
// 3512.588 us; speedup vs baseline: 3.8138x; 1.0661x over previous
//
#include <hip/hip_runtime.h>

// ---------------------------------------------------------------------------
// OGRENet GraphNet block — f16 MFMA, per-graph bias folding, L3-resident chunks.
//   edge layer0: [xr|xc|ea] (K=32p) @ W^T + ub0[graph]   (u-part folded, fp32)
//   edge MLP: -> 1024 x3 -> 512 (f16 mfma, K=1024)
//   node MLP1: [xcol|pad|edge_out] (K=544p) -> 512 -> 512(f32), scatter_mean
//   node MLP2: [x|pad|agg] (K=544p) @ W^T + ubm[graph] -> 512(f32) -> 1
// Chunked over edges (EC=25000) so activations stay in the 256MB L3.
// ---------------------------------------------------------------------------

#define NN 20000
#define EE 100000
#define BB 16

typedef _Float16 f16x8 __attribute__((ext_vector_type(8)));
typedef float f32x4 __attribute__((ext_vector_type(4)));

__device__ __forceinline__ int clampi(int v, int hi) {
    return v < 0 ? 0 : (v >= hi ? hi - 1 : v);
}

__device__ __forceinline__ void gld_lds16(const void* g, void* l) {
    __builtin_amdgcn_global_load_lds(
        (const __attribute__((address_space(1))) unsigned int*)g,
        (__attribute__((address_space(3))) unsigned int*)l, 16, 0, 0);
}

// ------------------------- f16 MFMA GEMM -----------------------------------
// C[M,N] = act(A[M,K] @ W^T + bias); A [M][lda] f16, W [N][ldb] f16.
// If gbid != NULL: bias row = bias + clamp(gbid[m])*ldbias (per-graph bias).
// 128x128 tile, 4 waves, 64x64/wave, mfma_16x16x32, BK=32, conflict-free LDS.
__global__ __launch_bounds__(256) void gemm_f16(
    const _Float16* __restrict__ A, int lda,
    const _Float16* __restrict__ Wt, int ldb,
    const float* __restrict__ bias, int ldbias, const int* __restrict__ gbid,
    void* __restrict__ C, int ldc,
    int M, int Kpad, int relu, int f32out)
{
    __shared__ _Float16 As[4096];
    __shared__ _Float16 Bs[4096];
    const int tid  = threadIdx.x;
    const int lane = tid & 63;
    const int wid  = tid >> 6;
    const int bm = blockIdx.y << 7;
    const int bn = blockIdx.x << 7;
    const int wm = (wid & 1) << 6;
    const int wn = (wid >> 1) << 6;

    f32x4 acc[4][4];
#pragma unroll
    for (int i = 0; i < 4; ++i)
#pragma unroll
        for (int j = 0; j < 4; ++j) acc[i][j] = (f32x4){0.f, 0.f, 0.f, 0.f};

    const int q0 = tid, q1 = 256 + tid;
    const int r0 = q0 & 127, kg0 = q0 >> 7;
    const int r1 = q1 & 127, kg1 = q1 >> 7;
    int am0 = bm + r0; if (am0 >= M) am0 = M - 1;
    int am1 = bm + r1; if (am1 >= M) am1 = M - 1;
    const _Float16* ga0 = A + (size_t)am0 * lda + (kg0 << 3);
    const _Float16* ga1 = A + (size_t)am1 * lda + (kg1 << 3);
    const _Float16* gb0 = Wt + (size_t)(bn + r0) * ldb + (kg0 << 3);
    const _Float16* gb1 = Wt + (size_t)(bn + r1) * ldb + (kg1 << 3);
    _Float16* la0 = As + ((wid * 64) << 3);
    _Float16* la1 = As + ((256 + wid * 64) << 3);
    _Float16* lb0 = Bs + ((wid * 64) << 3);
    _Float16* lb1 = Bs + ((256 + wid * 64) << 3);

    const int kq  = (lane >> 4) * 128;
    const int l15 = lane & 15;

    for (int k0 = 0; k0 < Kpad; k0 += 32) {
        __syncthreads();
        gld_lds16(ga0, la0);
        gld_lds16(ga1, la1);
        gld_lds16(gb0, lb0);
        gld_lds16(gb1, lb1);
        ga0 += 32; ga1 += 32; gb0 += 32; gb1 += 32;
        __syncthreads();

        f16x8 af[4], bf[4];
#pragma unroll
        for (int i = 0; i < 4; ++i)
            af[i] = *(const f16x8*)(As + (size_t)((kq + wm + i * 16 + l15) << 3));
#pragma unroll
        for (int j = 0; j < 4; ++j)
            bf[j] = *(const f16x8*)(Bs + (size_t)((kq + wn + j * 16 + l15) << 3));
#pragma unroll
        for (int i = 0; i < 4; ++i)
#pragma unroll
            for (int j = 0; j < 4; ++j)
                acc[i][j] = __builtin_amdgcn_mfma_f32_16x16x32_f16(af[i], bf[j], acc[i][j], 0, 0, 0);
    }

    const int l4 = (lane >> 4) << 2;
#pragma unroll
    for (int i = 0; i < 4; ++i) {
#pragma unroll
        for (int v = 0; v < 4; ++v) {
            const int m = bm + wm + i * 16 + l4 + v;
            if (m >= M) continue;
            const float* brow = bias;
            if (gbid) brow += (size_t)clampi(gbid[m], BB) * ldbias;
#pragma unroll
            for (int j = 0; j < 4; ++j) {
                const int col = bn + wn + j * 16 + l15;
                float val = acc[i][j][v] + brow[col];
                if (relu) val = fmaxf(val, 0.f);
                if (f32out) ((float*)C)[(size_t)m * ldc + col] = val;
                else        ((_Float16*)C)[(size_t)m * ldc + col] = (_Float16)val;
            }
        }
    }
}

// ------------------------- helper kernels ----------------------------------

// plain w[N,K] fp32 -> wh[N,Kpad] f16
__global__ void k_w2h(const float* __restrict__ w, _Float16* __restrict__ wh,
                      int N, int K, int Kpad)
{
    int t = blockIdx.x * blockDim.x + threadIdx.x;
    if (t >= N * Kpad) return;
    int n = t / Kpad, k = t - n * Kpad;
    wh[t] = (k < K) ? (_Float16)w[(size_t)n * K + k] : (_Float16)0.f;
}

// edge layer0: wh0[1024][32], cols 0..18 = ew0[:, :19], rest 0
__global__ void k_w2h_e0(const float* __restrict__ ew0, _Float16* __restrict__ wh0)
{
    int t = blockIdx.x * blockDim.x + threadIdx.x;
    if (t >= 1024 * 32) return;
    int n = t >> 5, c = t & 31;
    wh0[t] = (c < 19) ? (_Float16)ew0[(size_t)n * 275 + c] : (_Float16)0.f;
}

// packed 544 layout: dst[n][k]: k<9 -> src[n][k]; 16<=k<528 -> src[n][9+(k-16)]
__global__ void k_w2h_pack544(const float* __restrict__ src, _Float16* __restrict__ dst,
                              int N, int Ksrc)
{
    int t = blockIdx.x * blockDim.x + threadIdx.x;
    if (t >= N * 544) return;
    int n = t / 544, k = t - n * 544;
    float v = 0.f;
    if (k < 9)                 v = src[(size_t)n * Ksrc + k];
    else if (k >= 16 && k < 528) v = src[(size_t)n * Ksrc + 9 + (k - 16)];
    dst[t] = (_Float16)v;
}

// u_r[16,256] fp32
__global__ void k_u_r(const float* __restrict__ u, const float* __restrict__ w_sel,
                      const float* __restrict__ b_sel, float* __restrict__ u_r)
{
    int wave = (blockIdx.x * 256 + threadIdx.x) >> 6;
    int lane = threadIdx.x & 63;
    int b = wave >> 8, n = wave & 255;
    const float4* u4 = (const float4*)(u + (size_t)b * 4096);
    const float4* w4 = (const float4*)(w_sel + (size_t)n * 4096);
    float s = 0.f;
    for (int i = lane; i < 1024; i += 64) {
        float4 a = u4[i], c = w4[i];
        s += a.x * c.x + a.y * c.y + a.z * c.z + a.w * c.w;
    }
    for (int off = 32; off; off >>= 1) s += __shfl_down(s, off);
    if (lane == 0) u_r[b * 256 + n] = s + b_sel[n];
}

// ub[16][Nout] = u_r @ w[:, koff:koff+256]^T + b. one wave per (g,n).
__global__ void k_graph_bias(const float* __restrict__ u_r, const float* __restrict__ w,
                             const float* __restrict__ b, float* __restrict__ ub,
                             int Nout, int Ksrc, int koff)
{
    int wave = (blockIdx.x * 256 + threadIdx.x) >> 6;
    int lane = threadIdx.x & 63;
    if (wave >= 16 * Nout) return;
    int g = wave / Nout, n = wave - g * Nout;
    const float* ur = u_r + (size_t)g * 256;
    const float* wr = w + (size_t)n * Ksrc + koff;
    float s = 0.f;
#pragma unroll
    for (int i = 0; i < 4; ++i) {
        int k = lane * 4 + i;
        s += ur[k] * wr[k];
    }
    for (int off = 32; off; off >>= 1) s += __shfl_down(s, off);
    if (lane == 0) ub[(size_t)g * Nout + n] = s + b[n];
}

// gbe[e] = batch[row[e]]
__global__ void k_gbe(const int* __restrict__ row, const int* __restrict__ batch,
                      int* __restrict__ gbe)
{
    int e = blockIdx.x * blockDim.x + threadIdx.x;
    if (e < EE) gbe[e] = clampi(batch[clampi(row[e], NN)], BB);
}

// e_in[ec,32] f16 = [x[row](9) | x[col](9) | ea(1) | 0-pad]
__global__ void k_gather_edge_in(const float* __restrict__ x, const float* __restrict__ ea,
                                 const int* __restrict__ row, const int* __restrict__ col,
                                 _Float16* __restrict__ e_in, int e0, int ec)
{
    int t = blockIdx.x * blockDim.x + threadIdx.x;
    if (t >= ec * 32) return;
    int el = t >> 5, c = t & 31;
    int e = e0 + el;
    float v = 0.f;
    if (c < 9)        v = x[(size_t)clampi(row[e], NN) * 9 + c];
    else if (c < 18)  v = x[(size_t)clampi(col[e], NN) * 9 + (c - 9)];
    else if (c == 18) v = ea[e];
    e_in[t] = (_Float16)v;
}

// n_in[ec,544] f16 = [x[col](9) | pad7 | edge_out(512) | pad16], f16x8 chunks
__global__ void k_gather_node_in(const float* __restrict__ x,
                                 const _Float16* __restrict__ edge_out,
                                 const int* __restrict__ col,
                                 _Float16* __restrict__ n_in, int e0, int ec)
{
    int t = blockIdx.x * blockDim.x + threadIdx.x;
    if (t >= ec * 68) return;
    int el = t / 68, ck = t - el * 68;
    f16x8 v = (f16x8)(_Float16)0.f;
    if (ck == 0) {
        const float* xp = x + (size_t)clampi(col[e0 + el], NN) * 9;
#pragma unroll
        for (int j = 0; j < 8; ++j) v[j] = (_Float16)xp[j];
    } else if (ck == 1) {
        v[0] = (_Float16)x[(size_t)clampi(col[e0 + el], NN) * 9 + 8];
    } else if (ck < 66) {
        v = *(const f16x8*)(edge_out + (size_t)el * 512 + ((ck - 2) << 3));
    }
    *(f16x8*)(n_in + (size_t)el * 544 + (ck << 3)) = v;
}

// m_in[N,544] f16 = [x(9) | pad7 | agg/cnt(512) | pad16]
__global__ void k_gather_m_in(const float* __restrict__ x, const float* __restrict__ agg,
                              const float* __restrict__ cnt, _Float16* __restrict__ m_in)
{
    int t = blockIdx.x * blockDim.x + threadIdx.x;
    if (t >= NN * 68) return;
    int n = t / 68, ck = t - n * 68;
    f16x8 v = (f16x8)(_Float16)0.f;
    if (ck == 0) {
        const float* xp = x + (size_t)n * 9;
#pragma unroll
        for (int j = 0; j < 8; ++j) v[j] = (_Float16)xp[j];
    } else if (ck == 1) {
        v[0] = (_Float16)x[(size_t)n * 9 + 8];
    } else if (ck < 66) {
        float inv = 1.f / fmaxf(cnt[n], 1.f);
        const float4* ap = (const float4*)(agg + (size_t)n * 512 + ((ck - 2) << 3));
        float4 a0 = ap[0], a1 = ap[1];
        v[0] = (_Float16)(a0.x * inv); v[1] = (_Float16)(a0.y * inv);
        v[2] = (_Float16)(a0.z * inv); v[3] = (_Float16)(a0.w * inv);
        v[4] = (_Float16)(a1.x * inv); v[5] = (_Float16)(a1.y * inv);
        v[6] = (_Float16)(a1.z * inv); v[7] = (_Float16)(a1.w * inv);
    }
    *(f16x8*)(m_in + (size_t)n * 544 + (ck << 3)) = v;
}

__global__ void k_count(const int* __restrict__ row, float* __restrict__ cnt)
{
    int e = blockIdx.x * blockDim.x + threadIdx.x;
    if (e < EE) atomicAdd(&cnt[clampi(row[e], NN)], 1.f);
}

__global__ void k_scatter_add(const float* __restrict__ nh2, const int* __restrict__ row,
                              float* __restrict__ agg, int e0, int ec)
{
    int t = blockIdx.x * blockDim.x + threadIdx.x;
    if (t >= ec * 512) return;
    int el = t >> 9, c = t & 511;
    int r = clampi(row[e0 + el], NN);
    atomicAdd(&agg[(size_t)r * 512 + c], nh2[(size_t)el * 512 + c]);
}

// out[n] = h2[n,:] . mw1 + mb1 (fp32, one wave per node)
__global__ void k_final(const float* __restrict__ h2, const float* __restrict__ mw1,
                        const float* __restrict__ mb1, float* __restrict__ out)
{
    int wave = (blockIdx.x * 256 + threadIdx.x) >> 6;
    int lane = threadIdx.x & 63;
    if (wave >= NN) return;
    const float4* h4 = (const float4*)(h2 + (size_t)wave * 512);
    const float4* w4 = (const float4*)mw1;
    float s = 0.f;
#pragma unroll
    for (int i = 0; i < 2; ++i) {
        int f = lane * 2 + i;
        float4 a = h4[f], b = w4[f];
        s += a.x * b.x + a.y * b.y + a.z * b.z + a.w * b.w;
    }
    for (int off = 32; off; off >>= 1) s += __shfl_down(s, off);
    if (lane == 0) out[wave] = s + mb1[0];
}

// ------------------------------- host --------------------------------------

static inline void gemmF(hipStream_t s, const _Float16* A, int lda, const _Float16* Wt, int ldb,
                         const float* bias, int ldbias, const int* gbid,
                         void* C, int ldc, int M, int N, int K, int relu, int f32out)
{
    dim3 g(N / 128, (M + 127) / 128);
    hipLaunchKernelGGL(gemm_f16, g, dim3(256), 0, s, A, lda, Wt, ldb,
                       bias, ldbias, gbid, C, ldc, M, K, relu, f32out);
}

#define GRID1(n) dim3(((n) + 255) / 256)

extern "C" void kernel_launch(void* const* d_in, const int* in_sizes, int n_in,
                              void* d_out, int out_size, void* d_ws, size_t ws_size,
                              hipStream_t stream)
{
    const float* x     = (const float*)d_in[0];
    const int*   ei    = (const int*)d_in[1];
    const float* ea    = (const float*)d_in[2];
    const float* u     = (const float*)d_in[3];
    const int*   batch = (const int*)d_in[4];
    const float* w_sel = (const float*)d_in[5];
    const float* b_sel = (const float*)d_in[6];
    const float* ew0 = (const float*)d_in[7];   const float* eb0 = (const float*)d_in[8];
    const float* ew1 = (const float*)d_in[9];   const float* eb1 = (const float*)d_in[10];
    const float* ew2 = (const float*)d_in[11];  const float* eb2 = (const float*)d_in[12];
    const float* ew3 = (const float*)d_in[13];  const float* eb3 = (const float*)d_in[14];
    const float* ew4 = (const float*)d_in[15];  const float* eb4 = (const float*)d_in[16];
    const float* nw0 = (const float*)d_in[17];  const float* nb0 = (const float*)d_in[18];
    const float* nw1 = (const float*)d_in[19];  const float* nb1 = (const float*)d_in[20];
    const float* mw0 = (const float*)d_in[21];  const float* mb0 = (const float*)d_in[22];
    const float* mw1 = (const float*)d_in[23];  const float* mb1 = (const float*)d_in[24];

    const int* row = ei;
    const int* col = ei + EE;

    char* W = (char*)d_ws;
    size_t off = 0;
    auto alloc = [&](size_t bytes) -> char* {
        char* p = W + off;
        off = (off + bytes + 255) & ~(size_t)255;
        return p;
    };
    float*     cnt  = (float*)alloc(20000 * 4);
    float*     agg  = (float*)alloc((size_t)NN * 512 * 4);
    const size_t zeroBytes = off;
    float*     u_r  = (float*)alloc(16 * 256 * 4);
    float*     ub0  = (float*)alloc(16 * 1024 * 4);
    float*     ubm  = (float*)alloc(16 * 512 * 4);
    int*       gbe  = (int*)alloc((size_t)EE * 4);
    _Float16*  wh0  = (_Float16*)alloc((size_t)1024 * 32 * 2);
    _Float16*  wh1  = (_Float16*)alloc((size_t)1024 * 1024 * 2);
    _Float16*  wh2  = (_Float16*)alloc((size_t)1024 * 1024 * 2);
    _Float16*  wh3  = (_Float16*)alloc((size_t)1024 * 1024 * 2);
    _Float16*  wh4  = (_Float16*)alloc((size_t)512 * 1024 * 2);
    _Float16*  whn0 = (_Float16*)alloc((size_t)512 * 544 * 2);
    _Float16*  whn1 = (_Float16*)alloc((size_t)512 * 512 * 2);
    _Float16*  whm0 = (_Float16*)alloc((size_t)512 * 544 * 2);
    const size_t fixedBytes = off;

    // pick edge chunk: prefer 25000 (L3-resident working set)
    static const int ecOpts[] = {25000, 12500, 5000};
    int EC = 5000;
    for (int i = 0; i < 3; ++i) {
        int ec = ecOpts[i];
        size_t sE  = (size_t)ec * 32 * 2;
        size_t sA  = (size_t)ec * 1024 * 2; if (sA < (size_t)NN * 544 * 2) sA = (size_t)NN * 544 * 2;
        size_t sB  = (size_t)ec * 1024 * 2;
        size_t sEO = (size_t)ec * 512 * 2;
        size_t sD  = (size_t)ec * 512 * 4;  if (sD < (size_t)NN * 512 * 4) sD = (size_t)NN * 512 * 4;
        if (fixedBytes + sE + sA + sB + sEO + sD + 2048 <= ws_size) { EC = ec; break; }
    }
    size_t sE  = (size_t)EC * 32 * 2;
    size_t sA  = (size_t)EC * 1024 * 2; if (sA < (size_t)NN * 544 * 2) sA = (size_t)NN * 544 * 2;
    size_t sB  = (size_t)EC * 1024 * 2;
    size_t sEO = (size_t)EC * 512 * 2;
    size_t sD  = (size_t)EC * 512 * 4;  if (sD < (size_t)NN * 512 * 4) sD = (size_t)NN * 512 * 4;
    _Float16* bufE  = (_Float16*)alloc(sE);    // e_in [EC,32]
    _Float16* bufA  = (_Float16*)alloc(sA);    // ping  [EC,1024] / n_in,m_in [.,544]
    _Float16* bufB  = (_Float16*)alloc(sB);    // pong  [EC,1024]
    _Float16* bufEO = (_Float16*)alloc(sEO);   // edge_out [EC,512]
    float*    bufD  = (float*)alloc(sD);       // nh2 [EC,512] f32 / h2 [NN,512] f32
    const int NCH = EE / EC;

    hipMemsetAsync(W, 0, zeroBytes, stream);

    hipLaunchKernelGGL(k_u_r, dim3(1024), dim3(256), 0, stream, u, w_sel, b_sel, u_r);
    // per-graph biases (need u_r)
    hipLaunchKernelGGL(k_graph_bias, GRID1(16 * 1024 * 64), dim3(256), 0, stream,
                       u_r, ew0, eb0, ub0, 1024, 275, 19);
    hipLaunchKernelGGL(k_graph_bias, GRID1(16 * 512 * 64), dim3(256), 0, stream,
                       u_r, mw0, mb0, ubm, 512, 777, 521);
    hipLaunchKernelGGL(k_gbe, GRID1(EE), dim3(256), 0, stream, row, batch, gbe);

    hipLaunchKernelGGL(k_w2h_e0, GRID1(1024 * 32), dim3(256), 0, stream, ew0, wh0);
    auto cvt = [&](const float* w, _Float16* wh, int N, int K) {
        hipLaunchKernelGGL(k_w2h, GRID1(N * K), dim3(256), 0, stream, w, wh, N, K, K);
    };
    cvt(ew1, wh1, 1024, 1024);
    cvt(ew2, wh2, 1024, 1024);
    cvt(ew3, wh3, 1024, 1024);
    cvt(ew4, wh4, 512, 1024);
    hipLaunchKernelGGL(k_w2h_pack544, GRID1(512 * 544), dim3(256), 0, stream, nw0, whn0, 512, 521);
    cvt(nw1, whn1, 512, 512);
    hipLaunchKernelGGL(k_w2h_pack544, GRID1(512 * 544), dim3(256), 0, stream, mw0, whm0, 512, 777);

    hipLaunchKernelGGL(k_count, GRID1(EE), dim3(256), 0, stream, row, cnt);

    for (int ch = 0; ch < NCH; ++ch) {
        int e0 = ch * EC;
        hipLaunchKernelGGL(k_gather_edge_in, GRID1(EC * 32), dim3(256), 0, stream,
                           x, ea, row, col, bufE, e0, EC);
        gemmF(stream, bufE, 32,   wh0, 32,   ub0, 1024, gbe + e0, bufA, 1024, EC, 1024, 32, 1, 0);
        gemmF(stream, bufA, 1024, wh1, 1024, eb1, 0, nullptr, bufB, 1024, EC, 1024, 1024, 1, 0);
        gemmF(stream, bufB, 1024, wh2, 1024, eb2, 0, nullptr, bufA, 1024, EC, 1024, 1024, 1, 0);
        gemmF(stream, bufA, 1024, wh3, 1024, eb3, 0, nullptr, bufB, 1024, EC, 1024, 1024, 1, 0);
        gemmF(stream, bufB, 1024, wh4, 1024, eb4, 0, nullptr, bufEO, 512, EC, 512, 1024, 0, 0);
        hipLaunchKernelGGL(k_gather_node_in, GRID1(EC * 68), dim3(256), 0, stream,
                           x, bufEO, col, bufA, e0, EC);
        gemmF(stream, bufA, 544, whn0, 544, nb0, 0, nullptr, bufB, 512, EC, 512, 544, 1, 0);
        gemmF(stream, bufB, 512, whn1, 512, nb1, 0, nullptr, bufD, 512, EC, 512, 512, 1, 1);
        hipLaunchKernelGGL(k_scatter_add, GRID1(EC * 512), dim3(256), 0, stream,
                           bufD, row, agg, e0, EC);
    }

    // node MLP2: m_in [NN,544] (u-part folded into ubm per-graph bias)
    hipLaunchKernelGGL(k_gather_m_in, GRID1(NN * 68), dim3(256), 0, stream,
                       x, agg, cnt, bufA);
    gemmF(stream, bufA, 544, whm0, 544, ubm, 512, batch, bufD, 512, NN, 512, 544, 1, 1);
    hipLaunchKernelGGL(k_final, dim3((NN + 3) / 4), dim3(256), 0, stream,
                       bufD, mw1, mb1, (float*)d_out);
}

// Round 6
// 2085.112 us; speedup vs baseline: 6.4248x; 1.6846x over previous
//
#include <hip/hip_runtime.h>

// ---------------------------------------------------------------------------
// OGRENet GraphNet block — f16 MFMA with BLOCKED operand layout.
// Blocked layout (f16): offset(m,k) = ((mt*KT + kt)*4 + kg)*1024 + r*8 + ko
//   mt=m>>7, r=m&127, kt=k>>5, kg=(k>>3)&3, ko=k&7.   (tile = 128x32 = 8KB)
// Staging reads are 1KB-contiguous per global_load_lds; frag reads conflict-free.
// Epilogue mode 0 re-blocks C via LDS transpose; mode 1 = f32 row-major;
// mode 2 = fused scatter-add (atomicAdd into agg).
// XCD swizzle: 8 column-blocks of one M-panel land on the same XCD.
// ---------------------------------------------------------------------------

#define NN 20000
#define EE 100000
#define BB 16

typedef _Float16 f16x8 __attribute__((ext_vector_type(8)));
typedef _Float16 f16x4 __attribute__((ext_vector_type(4)));
typedef float f32x4 __attribute__((ext_vector_type(4)));

__device__ __forceinline__ int clampi(int v, int hi) {
    return v < 0 ? 0 : (v >= hi ? hi - 1 : v);
}

__device__ __forceinline__ void gld_lds16(const void* g, void* l) {
    __builtin_amdgcn_global_load_lds(
        (const __attribute__((address_space(1))) unsigned int*)g,
        (__attribute__((address_space(3))) unsigned int*)l, 16, 0, 0);
}

// ------------------------- blocked f16 MFMA GEMM ---------------------------
__global__ __launch_bounds__(256) void gemm_blk(
    const _Float16* __restrict__ A,      // blocked [MT][KT]
    const _Float16* __restrict__ Wt,     // blocked [NT][KT]
    int KT,
    const float* __restrict__ bias, int ldbias, const int* __restrict__ gbid,
    void* __restrict__ C, int KTo, int ktOff,   // mode 0: blocked f16 out
    int ldc,                                    // mode 1: f32 row-major out
    const int* __restrict__ srow, float* __restrict__ agg,  // mode 2
    int M, int relu, int mode)
{
    __shared__ char smem[33792];                 // 128*132*2 (>= 16KB staging)
    _Float16* As = (_Float16*)smem;              // 4096 f16
    _Float16* Bs = As + 4096;

    const int tid  = threadIdx.x;
    const int lane = tid & 63;
    const int wid  = tid >> 6;
    const int wm = (wid & 1) << 6;
    const int wn = (wid >> 1) << 6;

    // XCD swizzle: panel p's column-blocks share f%8 (same XCD)
    const int nb = gridDim.x;
    const int MT = gridDim.y;
    int f = blockIdx.y * nb + blockIdx.x;
    const int MT8 = MT & ~7;
    int p, c;
    if (f < MT8 * nb) {
        c = (f >> 3) % nb;
        p = (f & 7) + 8 * ((f >> 3) / nb);
    } else {
        int g = f - MT8 * nb;
        p = MT8 + g / nb;
        c = g % nb;
    }

    f32x4 acc[4][4];
#pragma unroll
    for (int i = 0; i < 4; ++i)
#pragma unroll
        for (int j = 0; j < 4; ++j) acc[i][j] = (f32x4){0.f, 0.f, 0.f, 0.f};

    const _Float16* pA = A + (size_t)p * KT * 4096;
    const _Float16* pB = Wt + (size_t)c * KT * 4096;
    const int cb0 = wid * 64;         // chunk base, inst 0
    const int cb1 = 256 + wid * 64;   // chunk base, inst 1
    const int kq  = (lane >> 4) * 128;
    const int l15 = lane & 15;
    const int l4  = (lane >> 4) << 2;

    for (int kt = 0; kt < KT; ++kt) {
        __syncthreads();
        gld_lds16(pA + (size_t)(cb0 + lane) * 8, As + cb0 * 8);
        gld_lds16(pA + (size_t)(cb1 + lane) * 8, As + cb1 * 8);
        gld_lds16(pB + (size_t)(cb0 + lane) * 8, Bs + cb0 * 8);
        gld_lds16(pB + (size_t)(cb1 + lane) * 8, Bs + cb1 * 8);
        pA += 4096; pB += 4096;
        __syncthreads();

        f16x8 af[4], bf[4];
#pragma unroll
        for (int i = 0; i < 4; ++i)
            af[i] = *(const f16x8*)(As + (size_t)((kq + wm + i * 16 + l15) << 3));
#pragma unroll
        for (int j = 0; j < 4; ++j)
            bf[j] = *(const f16x8*)(Bs + (size_t)((kq + wn + j * 16 + l15) << 3));
#pragma unroll
        for (int i = 0; i < 4; ++i)
#pragma unroll
            for (int j = 0; j < 4; ++j)
                acc[i][j] = __builtin_amdgcn_mfma_f32_16x16x32_f16(af[i], bf[j], acc[i][j], 0, 0, 0);
    }

    if (mode == 0) {
        // re-block C through LDS: [128][132] f16
        __syncthreads();
        _Float16* tr = (_Float16*)smem;
#pragma unroll
        for (int i = 0; i < 4; ++i) {
#pragma unroll
            for (int v = 0; v < 4; ++v) {
                const int rr = wm + i * 16 + l4 + v;
                const float* brow = bias;
                if (gbid) {
                    int m = p * 128 + rr; if (m >= M) m = M - 1;
                    brow = bias + (size_t)clampi(gbid[m], BB) * ldbias;
                }
#pragma unroll
                for (int j = 0; j < 4; ++j) {
                    const int cc = wn + j * 16 + l15;
                    float val = acc[i][j][v] + brow[c * 128 + cc];
                    if (relu) val = fmaxf(val, 0.f);
                    tr[rr * 132 + cc] = (_Float16)val;
                }
            }
        }
        __syncthreads();
#pragma unroll
        for (int it = 0; it < 8; ++it) {
            const int id = it * 256 + tid;
            const int r  = id & 127;
            const int cg = id >> 7;     // 0..15
            f16x4 lo = *(const f16x4*)(tr + r * 132 + cg * 8);
            f16x4 hi = *(const f16x4*)(tr + r * 132 + cg * 8 + 4);
            f16x8 v8;
#pragma unroll
            for (int t = 0; t < 4; ++t) { v8[t] = lo[t]; v8[t + 4] = hi[t]; }
            const int kti = ktOff + (c << 2) + (cg >> 2);
            size_t o = (((size_t)p * KTo + kti) * 4 + (cg & 3)) * 1024 + (size_t)r * 8;
            *(f16x8*)((_Float16*)C + o) = v8;
        }
    } else if (mode == 1) {
#pragma unroll
        for (int i = 0; i < 4; ++i) {
#pragma unroll
            for (int v = 0; v < 4; ++v) {
                const int m = p * 128 + wm + i * 16 + l4 + v;
                if (m >= M) continue;
                const float* brow = bias;
                if (gbid) brow = bias + (size_t)clampi(gbid[m], BB) * ldbias;
#pragma unroll
                for (int j = 0; j < 4; ++j) {
                    const int col = c * 128 + wn + j * 16 + l15;
                    float val = acc[i][j][v] + brow[col];
                    if (relu) val = fmaxf(val, 0.f);
                    ((float*)C)[(size_t)m * ldc + col] = val;
                }
            }
        }
    } else {
        // mode 2: relu(acc+bias) scatter-added into agg[srow[m]*512 + col]
#pragma unroll
        for (int i = 0; i < 4; ++i) {
#pragma unroll
            for (int v = 0; v < 4; ++v) {
                const int m = p * 128 + wm + i * 16 + l4 + v;
                if (m >= M) continue;
                const int r = clampi(srow[m], NN);
#pragma unroll
                for (int j = 0; j < 4; ++j) {
                    const int col = c * 128 + wn + j * 16 + l15;
                    float val = acc[i][j][v] + bias[col];
                    if (relu) val = fmaxf(val, 0.f);
                    atomicAdd(&agg[(size_t)r * 512 + col], val);
                }
            }
        }
    }
}

// ------------------------- helper kernels ----------------------------------

// fp32 w[N][Ksrc] -> blocked f16 [N/128][Kd/32] tiles.
// colmap mode: 0 plain (k<Ksrc), 1 e0 (k<19), 2 pack544 (k<9 | 32<=k<544 -> 9+(k-32))
__global__ void k_w2h_blk(const float* __restrict__ src, _Float16* __restrict__ dst,
                          int N, int Ksrc, int Kd, int mode)
{
    int t = blockIdx.x * blockDim.x + threadIdx.x;
    if (t >= N * Kd) return;
    int n = t / Kd, k = t - n * Kd;
    int sc = -1;
    if (mode == 0)      { if (k < Ksrc) sc = k; }
    else if (mode == 1) { if (k < 19) sc = k; }
    else                { if (k < 9) sc = k; else if (k >= 32 && k < 544) sc = 9 + (k - 32); }
    float v = (sc >= 0) ? src[(size_t)n * Ksrc + sc] : 0.f;
    int KT = Kd >> 5;
    int nt = n >> 7, r = n & 127, kt = k >> 5, kg = (k >> 3) & 3, ko = k & 7;
    dst[(((size_t)nt * KT + kt) * 4 + kg) * 1024 + (size_t)r * 8 + ko] = (_Float16)v;
}

// u_r[16,256] fp32
__global__ void k_u_r(const float* __restrict__ u, const float* __restrict__ w_sel,
                      const float* __restrict__ b_sel, float* __restrict__ u_r)
{
    int wave = (blockIdx.x * 256 + threadIdx.x) >> 6;
    int lane = threadIdx.x & 63;
    int b = wave >> 8, n = wave & 255;
    const float4* u4 = (const float4*)(u + (size_t)b * 4096);
    const float4* w4 = (const float4*)(w_sel + (size_t)n * 4096);
    float s = 0.f;
    for (int i = lane; i < 1024; i += 64) {
        float4 a = u4[i], c = w4[i];
        s += a.x * c.x + a.y * c.y + a.z * c.z + a.w * c.w;
    }
    for (int off = 32; off; off >>= 1) s += __shfl_down(s, off);
    if (lane == 0) u_r[b * 256 + n] = s + b_sel[n];
}

// ub[16][Nout] = u_r @ w[:, koff:koff+256]^T + b
__global__ void k_graph_bias(const float* __restrict__ u_r, const float* __restrict__ w,
                             const float* __restrict__ b, float* __restrict__ ub,
                             int Nout, int Ksrc, int koff)
{
    int wave = (blockIdx.x * 256 + threadIdx.x) >> 6;
    int lane = threadIdx.x & 63;
    if (wave >= 16 * Nout) return;
    int g = wave / Nout, n = wave - g * Nout;
    const float* ur = u_r + (size_t)g * 256;
    const float* wr = w + (size_t)n * Ksrc + koff;
    float s = 0.f;
#pragma unroll
    for (int i = 0; i < 4; ++i) s += ur[lane * 4 + i] * wr[lane * 4 + i];
    for (int off = 32; off; off >>= 1) s += __shfl_down(s, off);
    if (lane == 0) ub[(size_t)g * Nout + n] = s + b[n];
}

__global__ void k_gbe(const int* __restrict__ row, const int* __restrict__ batch,
                      int* __restrict__ gbe)
{
    int e = blockIdx.x * blockDim.x + threadIdx.x;
    if (e < EE) gbe[e] = clampi(batch[clampi(row[e], NN)], BB);
}

// e_in blocked [MT][1]: cols = [x[row](9) | x[col](9) | ea | 0..]
__global__ void k_gather_edge_blk(const float* __restrict__ x, const float* __restrict__ ea,
                                  const int* __restrict__ row, const int* __restrict__ col,
                                  _Float16* __restrict__ dst, int e0, int ec, int MTR)
{
    int t = blockIdx.x * blockDim.x + threadIdx.x;
    if (t >= MTR * 4) return;
    int r = t >> 2, kg = t & 3;
    int e = e0 + r; int emax = e0 + ec - 1;
    if (e > emax) e = emax;
    int ri = clampi(row[e], NN), ci = clampi(col[e], NN);
    f16x8 v;
#pragma unroll
    for (int j = 0; j < 8; ++j) {
        int cc = kg * 8 + j;
        float fv = 0.f;
        if (cc < 9)       fv = x[(size_t)ri * 9 + cc];
        else if (cc < 18) fv = x[(size_t)ci * 9 + (cc - 9)];
        else if (cc == 18) fv = ea[e];
        v[j] = (_Float16)fv;
    }
    *(f16x8*)(dst + (size_t)(r >> 7) * 4096 + (size_t)kg * 1024 + (size_t)(r & 127) * 8) = v;
}

// ninb kt0 (x[col] | pad) blocked; kt1..16 written by ew4's epilogue
__global__ void k_gather_nin0(const float* __restrict__ x, const int* __restrict__ col,
                              _Float16* __restrict__ dst, int e0, int ec, int MTR)
{
    int t = blockIdx.x * blockDim.x + threadIdx.x;
    if (t >= MTR * 4) return;
    int r = t >> 2, kg = t & 3;
    int e = e0 + r; int emax = e0 + ec - 1;
    if (e > emax) e = emax;
    int ci = clampi(col[e], NN);
    f16x8 v = (f16x8)(_Float16)0.f;
#pragma unroll
    for (int j = 0; j < 8; ++j) {
        int cc = kg * 8 + j;
        if (cc < 9) v[j] = (_Float16)x[(size_t)ci * 9 + cc];
    }
    *(f16x8*)(dst + ((size_t)(r >> 7) * 17) * 4096 + (size_t)kg * 1024 + (size_t)(r & 127) * 8) = v;
}

// m_in blocked [MTm][17]: cols = [x(9)|pad23 | agg/cnt(512)]
__global__ void k_gather_min(const float* __restrict__ x, const float* __restrict__ agg,
                             const float* __restrict__ cnt, _Float16* __restrict__ dst, int MTR)
{
    int t = blockIdx.x * blockDim.x + threadIdx.x;
    if (t >= MTR * 68) return;
    int r = t / 68, q = t - r * 68;
    int kt = q >> 2, kg = q & 3;
    int n = r < NN ? r : NN - 1;
    f16x8 v = (f16x8)(_Float16)0.f;
    if (kt == 0) {
#pragma unroll
        for (int j = 0; j < 8; ++j) {
            int cc = kg * 8 + j;
            if (cc < 9) v[j] = (_Float16)x[(size_t)n * 9 + cc];
        }
    } else {
        float inv = 1.f / fmaxf(cnt[n], 1.f);
        int cbase = (kt - 1) * 32 + kg * 8;
        const float4* ap = (const float4*)(agg + (size_t)n * 512 + cbase);
        float4 a0 = ap[0], a1 = ap[1];
        v[0] = (_Float16)(a0.x * inv); v[1] = (_Float16)(a0.y * inv);
        v[2] = (_Float16)(a0.z * inv); v[3] = (_Float16)(a0.w * inv);
        v[4] = (_Float16)(a1.x * inv); v[5] = (_Float16)(a1.y * inv);
        v[6] = (_Float16)(a1.z * inv); v[7] = (_Float16)(a1.w * inv);
    }
    *(f16x8*)(dst + ((size_t)(r >> 7) * 17 + kt) * 4096 + (size_t)kg * 1024 + (size_t)(r & 127) * 8) = v;
}

__global__ void k_count(const int* __restrict__ row, float* __restrict__ cnt)
{
    int e = blockIdx.x * blockDim.x + threadIdx.x;
    if (e < EE) atomicAdd(&cnt[clampi(row[e], NN)], 1.f);
}

// out[n] = h2[n,:] . mw1 + mb1
__global__ void k_final(const float* __restrict__ h2, const float* __restrict__ mw1,
                        const float* __restrict__ mb1, float* __restrict__ out)
{
    int wave = (blockIdx.x * 256 + threadIdx.x) >> 6;
    int lane = threadIdx.x & 63;
    if (wave >= NN) return;
    const float4* h4 = (const float4*)(h2 + (size_t)wave * 512);
    const float4* w4 = (const float4*)mw1;
    float s = 0.f;
#pragma unroll
    for (int i = 0; i < 2; ++i) {
        int f = lane * 2 + i;
        float4 a = h4[f], b = w4[f];
        s += a.x * b.x + a.y * b.y + a.z * b.z + a.w * b.w;
    }
    for (int off = 32; off; off >>= 1) s += __shfl_down(s, off);
    if (lane == 0) out[wave] = s + mb1[0];
}

// ------------------------------- host --------------------------------------

#define GRID1(n) dim3(((n) + 255) / 256)

static inline void gemmB(hipStream_t s, const _Float16* A, const _Float16* Wt, int KT,
                         const float* bias, int ldbias, const int* gbid,
                         void* C, int KTo, int ktOff, int ldc,
                         const int* srow, float* agg,
                         int M, int MT, int NT, int relu, int mode)
{
    hipLaunchKernelGGL(gemm_blk, dim3(NT, MT), dim3(256), 0, s,
                       A, Wt, KT, bias, ldbias, gbid, C, KTo, ktOff, ldc,
                       srow, agg, M, relu, mode);
}

extern "C" void kernel_launch(void* const* d_in, const int* in_sizes, int n_in,
                              void* d_out, int out_size, void* d_ws, size_t ws_size,
                              hipStream_t stream)
{
    const float* x     = (const float*)d_in[0];
    const int*   ei    = (const int*)d_in[1];
    const float* ea    = (const float*)d_in[2];
    const float* u     = (const float*)d_in[3];
    const int*   batch = (const int*)d_in[4];
    const float* w_sel = (const float*)d_in[5];
    const float* b_sel = (const float*)d_in[6];
    const float* ew0 = (const float*)d_in[7];   const float* eb0 = (const float*)d_in[8];
    const float* ew1 = (const float*)d_in[9];   const float* eb1 = (const float*)d_in[10];
    const float* ew2 = (const float*)d_in[11];  const float* eb2 = (const float*)d_in[12];
    const float* ew3 = (const float*)d_in[13];  const float* eb3 = (const float*)d_in[14];
    const float* ew4 = (const float*)d_in[15];  const float* eb4 = (const float*)d_in[16];
    const float* nw0 = (const float*)d_in[17];  const float* nb0 = (const float*)d_in[18];
    const float* nw1 = (const float*)d_in[19];  const float* nb1 = (const float*)d_in[20];
    const float* mw0 = (const float*)d_in[21];  const float* mb0 = (const float*)d_in[22];
    const float* mw1 = (const float*)d_in[23];  const float* mb1 = (const float*)d_in[24];

    const int* row = ei;
    const int* col = ei + EE;

    char* W = (char*)d_ws;
    size_t off = 0;
    auto alloc = [&](size_t bytes) -> char* {
        char* p = W + off;
        off = (off + bytes + 255) & ~(size_t)255;
        return p;
    };
    float*    cnt  = (float*)alloc(20000 * 4);
    float*    agg  = (float*)alloc((size_t)NN * 512 * 4);
    const size_t zeroBytes = off;
    float*    u_r  = (float*)alloc(16 * 256 * 4);
    float*    ub0  = (float*)alloc(16 * 1024 * 4);
    float*    ubm  = (float*)alloc(16 * 512 * 4);
    int*      gbe  = (int*)alloc((size_t)EE * 4);
    _Float16* wh0  = (_Float16*)alloc((size_t)8 * 1 * 4096 * 2);
    _Float16* wh1  = (_Float16*)alloc((size_t)8 * 32 * 4096 * 2);
    _Float16* wh2  = (_Float16*)alloc((size_t)8 * 32 * 4096 * 2);
    _Float16* wh3  = (_Float16*)alloc((size_t)8 * 32 * 4096 * 2);
    _Float16* wh4  = (_Float16*)alloc((size_t)4 * 32 * 4096 * 2);
    _Float16* whn0 = (_Float16*)alloc((size_t)4 * 17 * 4096 * 2);
    _Float16* whn1 = (_Float16*)alloc((size_t)4 * 16 * 4096 * 2);
    _Float16* whm0 = (_Float16*)alloc((size_t)4 * 17 * 4096 * 2);
    const int MTm = (NN + 127) / 128;           // 157
    float*    h2   = (float*)alloc((size_t)NN * 512 * 4);
    _Float16* m_in = (_Float16*)alloc((size_t)MTm * 17 * 4096 * 2);
    const size_t fixedBytes = off;

    // choose edge chunk (depends only on ws_size -> capture-safe)
    static const int ecOpts[] = {50000, 25000, 12500, 10000, 5000};
    int EC = 5000;
    for (int i = 0; i < 5; ++i) {
        int ec = ecOpts[i];
        size_t MTRc = (size_t)((ec + 127) / 128) * 128;
        size_t need = fixedBytes + MTRc * 32 * 2 + 2 * (MTRc * 1024 * 2) + MTRc * 544 * 2 + 4096;
        if (need <= ws_size) { EC = ec; break; }
    }
    const int MT  = (EC + 127) / 128;
    const size_t MTR = (size_t)MT * 128;
    _Float16* e_in = (_Float16*)alloc(MTR * 32 * 2);    // [MT][1]
    _Float16* ping = (_Float16*)alloc(MTR * 1024 * 2);  // [MT][32]
    _Float16* pong = (_Float16*)alloc(MTR * 1024 * 2);  // [MT][32]
    _Float16* ninb = (_Float16*)alloc(MTR * 544 * 2);   // [MT][17]
    const int NCH = (EE + EC - 1) / EC;

    (void)hipMemsetAsync(W, 0, zeroBytes, stream);

    hipLaunchKernelGGL(k_u_r, dim3(1024), dim3(256), 0, stream, u, w_sel, b_sel, u_r);
    hipLaunchKernelGGL(k_graph_bias, GRID1(16 * 1024 * 64), dim3(256), 0, stream,
                       u_r, ew0, eb0, ub0, 1024, 275, 19);
    hipLaunchKernelGGL(k_graph_bias, GRID1(16 * 512 * 64), dim3(256), 0, stream,
                       u_r, mw0, mb0, ubm, 512, 777, 521);
    hipLaunchKernelGGL(k_gbe, GRID1(EE), dim3(256), 0, stream, row, batch, gbe);

    auto pack = [&](const float* w, _Float16* wh, int N, int Ksrc, int Kd, int mode) {
        hipLaunchKernelGGL(k_w2h_blk, GRID1(N * Kd), dim3(256), 0, stream, w, wh, N, Ksrc, Kd, mode);
    };
    pack(ew0, wh0, 1024, 275, 32, 1);
    pack(ew1, wh1, 1024, 1024, 1024, 0);
    pack(ew2, wh2, 1024, 1024, 1024, 0);
    pack(ew3, wh3, 1024, 1024, 1024, 0);
    pack(ew4, wh4, 512, 1024, 1024, 0);
    pack(nw0, whn0, 512, 521, 544, 2);
    pack(nw1, whn1, 512, 512, 512, 0);
    pack(mw0, whm0, 512, 777, 544, 2);

    hipLaunchKernelGGL(k_count, GRID1(EE), dim3(256), 0, stream, row, cnt);

    for (int ch = 0; ch < NCH; ++ch) {
        int e0 = ch * EC;
        int ec = EC; if (e0 + ec > EE) ec = EE - e0;
        hipLaunchKernelGGL(k_gather_edge_blk, GRID1((int)MTR * 4), dim3(256), 0, stream,
                           x, ea, row, col, e_in, e0, ec, (int)MTR);
        // l0: K=32, per-graph bias ub0
        gemmB(stream, e_in, wh0, 1, ub0, 1024, gbe + e0, ping, 32, 0, 0, nullptr, nullptr,
              ec, MT, 8, 1, 0);
        gemmB(stream, ping, wh1, 32, eb1, 0, nullptr, pong, 32, 0, 0, nullptr, nullptr,
              ec, MT, 8, 1, 0);
        gemmB(stream, pong, wh2, 32, eb2, 0, nullptr, ping, 32, 0, 0, nullptr, nullptr,
              ec, MT, 8, 1, 0);
        gemmB(stream, ping, wh3, 32, eb3, 0, nullptr, pong, 32, 0, 0, nullptr, nullptr,
              ec, MT, 8, 1, 0);
        // ew4 -> ninb (blocked, kt offset 1), no relu (reference: no relu on edge_out)
        gemmB(stream, pong, wh4, 32, eb4, 0, nullptr, ninb, 17, 1, 0, nullptr, nullptr,
              ec, MT, 4, 0, 0);
        hipLaunchKernelGGL(k_gather_nin0, GRID1((int)MTR * 4), dim3(256), 0, stream,
                           x, col, ninb, e0, ec, (int)MTR);
        gemmB(stream, ninb, whn0, 17, nb0, 0, nullptr, ping, 16, 0, 0, nullptr, nullptr,
              ec, MT, 4, 1, 0);
        // n1: fused scatter-add into agg
        gemmB(stream, ping, whn1, 16, nb1, 0, nullptr, nullptr, 0, 0, 0, row + e0, agg,
              ec, MT, 4, 1, 2);
    }

    hipLaunchKernelGGL(k_gather_min, GRID1((int)(MTm * 128) * 68), dim3(256), 0, stream,
                       x, agg, cnt, m_in, MTm * 128);
    // m0: f32 row-major out, per-graph bias ubm (gbid = batch)
    gemmB(stream, m_in, whm0, 17, ubm, 512, batch, h2, 0, 0, 512, nullptr, nullptr,
          NN, MTm, 4, 1, 1);
    hipLaunchKernelGGL(k_final, dim3((NN + 3) / 4), dim3(256), 0, stream,
                       h2, mw1, mb1, (float*)d_out);
}